// Round 7
// baseline (107.751 us; speedup 1.0000x reference)
//
#include <hip/hip_runtime.h>

// VectorQuantizer round 7: 8 waves/SIMD occupancy push.
// x [32,64,4096] f32, emb [512,64] f32. N = 131072 rows (n = b*4096+t), D=64, K=512.
// prep: emb -> bf16 MFMA-fragment table + ctab[k] = 4 - ||e_k||^2/2 + zero buckets.
// main: 2048 blocks x 256 thr, 4 independent waves (no __syncthreads),
//   wave owns 16 rows, scans all 512 cods via mantissa-keyed fmax
//   (low 10 mantissa bits = 1023-cod -> argmax==first-min argmin, no index regs).
//   Target <=64 VGPR for 8 waves/SIMD.
// out[0..N*64) = emb[argmin][:] fp32 exact; out[N*64] = 1.25*mean((q-x_lin)^2).

#define VQ_OUTQ 8388608

typedef __attribute__((ext_vector_type(8))) short short8;
typedef __attribute__((ext_vector_type(4))) float f32x4;

__device__ __forceinline__ unsigned pk_bf16(float a, float b) {
    union { float f; unsigned u; } x, y; x.f = a; y.f = b;
    return ((y.u + 0x8000u) & 0xFFFF0000u) | ((x.u + 0x8000u) >> 16);
}

// ---- prep: fragment table + score-bias table + zero loss buckets ---------
__global__ __launch_bounds__(256) void vq_prep(
    const float* __restrict__ emb,
    short8* __restrict__ frag,      // 4096 slots x 16B
    float* __restrict__ ctab,       // 512: 4 - ||e_k||^2 / 2
    double* __restrict__ buck)      // 256
{
    const int s = blockIdx.x * 256 + threadIdx.x;   // 0..4095
    const int l = s & 63, kc = (s >> 6) & 1, ct = s >> 7;
    const int qs = l >> 4, ms = l & 15;
    const float* __restrict__ er = emb + (ct * 16 + ms) * 64 + kc * 32 + qs * 8;
    float4 p0 = *(const float4*)er;
    float4 p1 = *(const float4*)(er + 4);
    union { short8 s8; unsigned u[4]; } w;
    w.u[0] = pk_bf16(p0.x, p0.y); w.u[1] = pk_bf16(p0.z, p0.w);
    w.u[2] = pk_bf16(p1.x, p1.y); w.u[3] = pk_bf16(p1.z, p1.w);
    frag[s] = w.s8;

    if (s < 512) {
        const float4* __restrict__ e4 = (const float4*)emb + s * 16;
        float c = 0.f;
        #pragma unroll
        for (int i = 0; i < 16; ++i) {
            float4 e = e4[i];
            c = fmaf(e.x, e.x, c); c = fmaf(e.y, e.y, c);
            c = fmaf(e.z, e.z, c); c = fmaf(e.w, e.w, c);
        }
        ctab[s] = fmaf(-0.5f, c, 4.0f);
    }
    if (s < 256) buck[s] = 0.0;
}

// ---- main ----------------------------------------------------------------
__global__ __launch_bounds__(256, 8) void vq_main(
    const float* __restrict__ x,
    const float* __restrict__ emb,
    const short8* __restrict__ frag,
    const float* __restrict__ ctab,
    float* __restrict__ qout,
    double* __restrict__ buck)
{
    __shared__ int idxs[4][16];     // wave-private (DS in-order per wave)

    const int tid  = threadIdx.x;
    const int lane = tid & 63, wave = tid >> 6;
    const int m = lane & 15, quad = lane >> 4;

    const int rowbase = blockIdx.x * 64 + wave * 16;   // 16 rows/wave
    const int b = rowbase >> 12, t = rowbase & 4095;

    // ---- A-frags: x[b, d, t+m] direct global -> bf16 (16 strided dwords)
    short8 a[2];
    {
        const float* __restrict__ xa = x + (size_t)b * 262144 + t + m;
        #pragma unroll
        for (int kc = 0; kc < 2; ++kc) {
            const float* __restrict__ p = xa + (size_t)(kc * 32 + quad * 8) * 4096;
            float f[8];
            #pragma unroll
            for (int j = 0; j < 8; ++j) f[j] = p[(size_t)j * 4096];
            union { short8 s8; unsigned u[4]; } w;
            w.u[0] = pk_bf16(f[0], f[1]); w.u[1] = pk_bf16(f[2], f[3]);
            w.u[2] = pk_bf16(f[4], f[5]); w.u[3] = pk_bf16(f[6], f[7]);
            a[kc] = w.s8;
        }
    }

    // ---- scan: pure fmax over mantissa-keyed scores
    float best[4];
    best[0] = best[1] = best[2] = best[3] = 0.f;       // all real keys > 3

    #pragma unroll 2
    for (int g = 0; g < 16; ++g) {
        const int ct0 = g * 2, ct1 = g * 2 + 1;
        short8 b00 = frag[ct0 * 128 + lane];
        short8 b01 = frag[ct0 * 128 + 64 + lane];
        short8 b10 = frag[ct1 * 128 + lane];
        short8 b11 = frag[ct1 * 128 + 64 + lane];
        const float c0 = ctab[(ct0 << 4) + m];
        const float c1 = ctab[(ct1 << 4) + m];
        const unsigned f0 = 1023u - (unsigned)((ct0 << 4) + m);
        const unsigned f1 = 1023u - (unsigned)((ct1 << 4) + m);
        f32x4 p = {0.f, 0.f, 0.f, 0.f}, q = {0.f, 0.f, 0.f, 0.f};
        p = __builtin_amdgcn_mfma_f32_16x16x32_bf16(a[0], b00, p, 0, 0, 0);
        p = __builtin_amdgcn_mfma_f32_16x16x32_bf16(a[1], b01, p, 0, 0, 0);
        q = __builtin_amdgcn_mfma_f32_16x16x32_bf16(a[0], b10, q, 0, 0, 0);
        q = __builtin_amdgcn_mfma_f32_16x16x32_bf16(a[1], b11, q, 0, 0, 0);
        #pragma unroll
        for (int r = 0; r < 4; ++r) {
            float v0 = p[r] + c0;
            float v1 = q[r] + c1;
            float k0 = __uint_as_float((__float_as_uint(v0) & 0xFFFFFC00u) | f0);
            float k1 = __uint_as_float((__float_as_uint(v1) & 0xFFFFFC00u) | f1);
            best[r] = fmaxf(best[r], fmaxf(k0, k1));   // v_max3
        }
    }

    // ---- cross-m max-reduce; idx from winner's mantissa
    #pragma unroll
    for (int r = 0; r < 4; ++r) {
        float bv = best[r];
        #pragma unroll
        for (int mm = 1; mm < 16; mm <<= 1)
            bv = fmaxf(bv, __shfl_xor(bv, mm, 64));
        if (m == 0)
            idxs[wave][(quad << 2) + r] =
                1023 - (int)(__float_as_uint(bv) & 1023u);
    }
    // no barrier: wave-private LDS

    // ---- epilogue: wave's 16 rows = 4 KB contiguous; fused loss vs linear x
    {
        const float4* __restrict__ x4 = (const float4*)x + (size_t)rowbase * 16;
        float4* __restrict__ q4 = (float4*)qout + (size_t)rowbase * 16;
        const float4* __restrict__ e4 = (const float4*)emb;
        float ls = 0.f;
        #pragma unroll
        for (int j = 0; j < 4; ++j) {
            const int e = j * 64 + lane;       // float4 units, 0..255
            const int idx = idxs[wave][e >> 4];
            float4 q  = e4[idx * 16 + (e & 15)];
            float4 xr = x4[e];
            q4[e] = q;
            float dx = q.x - xr.x, dy = q.y - xr.y;
            float dz = q.z - xr.z, dw = q.w - xr.w;
            ls = fmaf(dx, dx, ls); ls = fmaf(dy, dy, ls);
            ls = fmaf(dz, dz, ls); ls = fmaf(dw, dw, ls);
        }
        #pragma unroll
        for (int off = 32; off > 0; off >>= 1)
            ls += __shfl_down(ls, off, 64);
        if (lane == 0)
            atomicAdd(&buck[(blockIdx.x * 4 + wave) & 255], (double)ls);
    }
}

// ---- finalize ------------------------------------------------------------
__global__ void vq_finalize(const double* __restrict__ buck,
                            float* __restrict__ out)
{
    const int lane = threadIdx.x & 63;
    double s = buck[lane] + buck[64 + lane] + buck[128 + lane] + buck[192 + lane];
    #pragma unroll
    for (int off = 32; off > 0; off >>= 1)
        s += __shfl_down(s, off, 64);
    if (lane == 0)
        out[VQ_OUTQ] = (float)(1.25 * s / 8388608.0);
}

extern "C" void kernel_launch(void* const* d_in, const int* in_sizes, int n_in,
                              void* d_out, int out_size, void* d_ws, size_t ws_size,
                              hipStream_t stream)
{
    const float* x   = (const float*)d_in[0];
    const float* emb = (const float*)d_in[1];
    float* out = (float*)d_out;

    short8* frag = (short8*)d_ws;                          // 65536 B
    float*  ctab = (float*)((char*)d_ws + 65536);          // 2048 B
    double* buck = (double*)((char*)d_ws + 65536 + 2048);  // 2048 B

    vq_prep<<<dim3(16), dim3(256), 0, stream>>>(emb, frag, ctab, buck);
    vq_main<<<dim3(2048), dim3(256), 0, stream>>>(x, emb, frag, ctab, out, buck);
    vq_finalize<<<dim3(1), dim3(64), 0, stream>>>(buck, out);
}

// Round 8
// 99.403 us; speedup vs baseline: 1.0840x; 1.0840x over previous
//
#include <hip/hip_runtime.h>

// VectorQuantizer round 8: LDS-staged pre-packed fragment table.
// x [32,64,4096] f32, emb [512,64] f32. N = 131072 rows (n = b*4096+t), D=64, K=512.
// prep: emb -> bf16 MFMA-fragment table (64KB) + ctab[k] = 4 - ||e_k||^2/2.
// main: 512 blocks x 512 thr (8 waves). Block stages frag table + ctab into LDS
//   (linear copy, one barrier), each wave scans its 32 rows x all 512 cods from
//   LDS via mantissa-keyed fmax (low 10 mantissa bits = 1023-cod ->
//   argmax == first-min argmin). 67KB LDS -> 2 blocks/CU = 16 waves/CU.
// out[0..N*64) = emb[argmin][:] fp32 exact; out[N*64] = 1.25*mean((q-x_lin)^2).

#define VQ_OUTQ 8388608

typedef __attribute__((ext_vector_type(8))) short short8;
typedef __attribute__((ext_vector_type(4))) float f32x4;

__device__ __forceinline__ unsigned pk_bf16(float a, float b) {
    union { float f; unsigned u; } x, y; x.f = a; y.f = b;
    return ((y.u + 0x8000u) & 0xFFFF0000u) | ((x.u + 0x8000u) >> 16);
}

// ---- prep: fragment table + score-bias table + zero loss buckets ---------
__global__ __launch_bounds__(256) void vq_prep(
    const float* __restrict__ emb,
    short8* __restrict__ frag,      // 4096 slots x 16B
    float* __restrict__ ctab,       // 512: 4 - ||e_k||^2 / 2
    double* __restrict__ buck)      // 256
{
    const int s = blockIdx.x * 256 + threadIdx.x;   // 0..4095
    const int l = s & 63, kc = (s >> 6) & 1, ct = s >> 7;
    const int qs = l >> 4, ms = l & 15;
    const float* __restrict__ er = emb + (ct * 16 + ms) * 64 + kc * 32 + qs * 8;
    float4 p0 = *(const float4*)er;
    float4 p1 = *(const float4*)(er + 4);
    union { short8 s8; unsigned u[4]; } w;
    w.u[0] = pk_bf16(p0.x, p0.y); w.u[1] = pk_bf16(p0.z, p0.w);
    w.u[2] = pk_bf16(p1.x, p1.y); w.u[3] = pk_bf16(p1.z, p1.w);
    frag[s] = w.s8;

    if (s < 512) {
        const float4* __restrict__ e4 = (const float4*)emb + s * 16;
        float c = 0.f;
        #pragma unroll
        for (int i = 0; i < 16; ++i) {
            float4 e = e4[i];
            c = fmaf(e.x, e.x, c); c = fmaf(e.y, e.y, c);
            c = fmaf(e.z, e.z, c); c = fmaf(e.w, e.w, c);
        }
        ctab[s] = fmaf(-0.5f, c, 4.0f);
    }
    if (s < 256) buck[s] = 0.0;
}

// ---- main ----------------------------------------------------------------
__global__ __launch_bounds__(512, 2) void vq_main(
    const float* __restrict__ x,
    const float* __restrict__ emb,
    const short8* __restrict__ frag,
    const float* __restrict__ ctab,
    float* __restrict__ qout,
    double* __restrict__ buck)
{
    __shared__ __align__(16) short8 sfrag[4096];   // 65536 B
    __shared__ float cks[512];                     // 2048 B
    __shared__ int idxs[8][32];                    // wave-private

    const int tid  = threadIdx.x;
    const int lane = tid & 63, wave = tid >> 6;
    const int m = lane & 15, quad = lane >> 4;

    const int rowbase = blockIdx.x * 256 + wave * 32;   // 32 rows/wave
    const int b = rowbase >> 12, t = rowbase & 4095;

    // ---- stage frag table + ctab into LDS (linear, conflict-free)
    #pragma unroll
    for (int i = 0; i < 8; ++i) {
        const int s = i * 512 + tid;
        sfrag[s] = frag[s];
    }
    cks[tid] = ctab[tid];                 // first 512 entries; 512 thr = exact
    __syncthreads();

    // ---- A-frags: x[b, d, t+row] direct global -> bf16
    short8 a[2][2];
    {
        const float* __restrict__ xa = x + (size_t)b * 262144 + t + m;
        #pragma unroll
        for (int rt = 0; rt < 2; ++rt) {
            #pragma unroll
            for (int kc = 0; kc < 2; ++kc) {
                const float* __restrict__ p =
                    xa + rt * 16 + (size_t)(kc * 32 + quad * 8) * 4096;
                float f[8];
                #pragma unroll
                for (int j = 0; j < 8; ++j) f[j] = p[(size_t)j * 4096];
                union { short8 s8; unsigned u[4]; } w;
                w.u[0] = pk_bf16(f[0], f[1]); w.u[1] = pk_bf16(f[2], f[3]);
                w.u[2] = pk_bf16(f[4], f[5]); w.u[3] = pk_bf16(f[6], f[7]);
                a[rt][kc] = w.s8;
            }
        }
    }

    // ---- scan all 512 cods from LDS: mantissa-keyed fmax
    float best[2][4];
    #pragma unroll
    for (int rt = 0; rt < 2; ++rt)
        #pragma unroll
        for (int r = 0; r < 4; ++r) best[rt][r] = 0.f;   // all real keys > 3

    #pragma unroll 4
    for (int ct = 0; ct < 32; ++ct) {
        short8 b0 = sfrag[ct * 128 + lane];
        short8 b1 = sfrag[ct * 128 + 64 + lane];
        const int cod = (ct << 4) + m;
        const float ck = cks[cod];
        const unsigned fk = 1023u - (unsigned)cod;
        #pragma unroll
        for (int rt = 0; rt < 2; ++rt) {
            f32x4 p = {0.f, 0.f, 0.f, 0.f};
            p = __builtin_amdgcn_mfma_f32_16x16x32_bf16(a[rt][0], b0, p, 0, 0, 0);
            p = __builtin_amdgcn_mfma_f32_16x16x32_bf16(a[rt][1], b1, p, 0, 0, 0);
            #pragma unroll
            for (int r = 0; r < 4; ++r) {
                float v = p[r] + ck;
                float k = __uint_as_float((__float_as_uint(v) & 0xFFFFFC00u) | fk);
                best[rt][r] = fmaxf(best[rt][r], k);
            }
        }
    }

    // ---- cross-m max-reduce; idx from winner's mantissa
    #pragma unroll
    for (int rt = 0; rt < 2; ++rt) {
        #pragma unroll
        for (int r = 0; r < 4; ++r) {
            float bv = best[rt][r];
            #pragma unroll
            for (int mm = 1; mm < 16; mm <<= 1)
                bv = fmaxf(bv, __shfl_xor(bv, mm, 64));
            if (m == 0)
                idxs[wave][rt * 16 + (quad << 2) + r] =
                    1023 - (int)(__float_as_uint(bv) & 1023u);
        }
    }
    // no barrier needed: idxs is wave-private, DS ops in-order per wave

    // ---- epilogue: wave's 32 rows = 8 KB contiguous; fused loss vs linear x
    {
        const float4* __restrict__ x4 = (const float4*)x + (size_t)rowbase * 16;
        float4* __restrict__ q4 = (float4*)qout + (size_t)rowbase * 16;
        const float4* __restrict__ e4 = (const float4*)emb;
        float ls = 0.f;
        #pragma unroll
        for (int j = 0; j < 8; ++j) {
            const int e = j * 64 + lane;       // float4 units, 0..511
            const int idx = idxs[wave][e >> 4];
            float4 q  = e4[idx * 16 + (e & 15)];
            float4 xr = x4[e];
            q4[e] = q;
            float dx = q.x - xr.x, dy = q.y - xr.y;
            float dz = q.z - xr.z, dw = q.w - xr.w;
            ls = fmaf(dx, dx, ls); ls = fmaf(dy, dy, ls);
            ls = fmaf(dz, dz, ls); ls = fmaf(dw, dw, ls);
        }
        #pragma unroll
        for (int off = 32; off > 0; off >>= 1)
            ls += __shfl_down(ls, off, 64);
        if (lane == 0)
            atomicAdd(&buck[(blockIdx.x * 8 + wave) & 255], (double)ls);
    }
}

// ---- finalize ------------------------------------------------------------
__global__ void vq_finalize(const double* __restrict__ buck,
                            float* __restrict__ out)
{
    const int lane = threadIdx.x & 63;
    double s = buck[lane] + buck[64 + lane] + buck[128 + lane] + buck[192 + lane];
    #pragma unroll
    for (int off = 32; off > 0; off >>= 1)
        s += __shfl_down(s, off, 64);
    if (lane == 0)
        out[VQ_OUTQ] = (float)(1.25 * s / 8388608.0);
}

extern "C" void kernel_launch(void* const* d_in, const int* in_sizes, int n_in,
                              void* d_out, int out_size, void* d_ws, size_t ws_size,
                              hipStream_t stream)
{
    const float* x   = (const float*)d_in[0];
    const float* emb = (const float*)d_in[1];
    float* out = (float*)d_out;

    short8* frag = (short8*)d_ws;                          // 65536 B
    float*  ctab = (float*)((char*)d_ws + 65536);          // 2048 B
    double* buck = (double*)((char*)d_ws + 65536 + 2048);  // 2048 B

    vq_prep<<<dim3(16), dim3(256), 0, stream>>>(emb, frag, ctab, buck);
    vq_main<<<dim3(512), dim3(512), 0, stream>>>(x, emb, frag, ctab, out, buck);
    vq_finalize<<<dim3(1), dim3(64), 0, stream>>>(buck, out);
}